// Round 8
// baseline (199.350 us; speedup 1.0000x reference)
//
#include <hip/hip_runtime.h>

// AdaptedGaussianConditional: v = inputs - means; nearest-codebook symbol via
// exact lower_bound semantics (tie -> lower index); dequant = codebook[sym] + means.
// Outputs concatenated: [dequant fp32 N | symbols-as-f32 N].
//
// R8 == R7 resubmitted (infra failure, kernel never benched).
// R7: zero-LDS hot path. R0-R6 pinned at 60-70us across every compute/LDS
// structure; all pipes <=35% busy. Remove the LDS pipe from the equation:
// LUT lives in GLOBAL memory served by L1 (16 KB, vmcnt-pipelined, no bank
// conflicts, no staging, no barrier, no LDS occupancy cap). Streaming loads
// use nontemporal hint to keep L1 for the LUT. Stores: normal cached float4
// (nt stores regressed in R6). Rare fallback scan + tail read uv[] global.
// lo/scale derived per-thread from uv[0]/uv[255] (uniform scalar L1 loads).

#define LVL 256
#define NB  512
#define QPT 4

typedef float f32x4 __attribute__((ext_vector_type(4)));

// Shared by build & main kernels — MUST be bit-identical in both.
__device__ __forceinline__ int bucket_of(float v, float lo, float scale) {
    int b = (int)floorf((v - lo) * scale);
    return min(max(b, 0), NB - 1);
}

// ---------------- build kernel: NB/256 blocks ----------------
// lutA[b] = {p0, p1, c0, c1}   lutB[b] = {c2, c3, unused, basepack}
// basepack int >= 0 : branchless entry, base = basepack + sel
// basepack int <  0 : fallback, exact scan start = -basepack - 1
__global__ __launch_bounds__(256) void agc_build_lut(
    const float* __restrict__ uv, float4* __restrict__ lutA, float4* __restrict__ lutB)
{
    __shared__ float s_uv[LVL];
    __shared__ int   s_b[LVL];
    int t = threadIdx.x;
    s_uv[t] = uv[t];
    __syncthreads();
    const float lo    = s_uv[0];
    const float scale = (float)NB / (s_uv[LVL - 1] - lo);
    s_b[t] = bucket_of(s_uv[t], lo, scale);
    __syncthreads();

    int b = blockIdx.x * 256 + t;
    if (b >= NB) return;

    int A = 0, cnt = 0;
    for (int j = 0; j < LVL; ++j) {
        int bj = s_b[j];
        A   += (bj <  b);
        cnt += (bj == b);
    }

    const float INF = __builtin_inff();
    float4 ea, eb;
    if (cnt == 0) {
        int idx = min(max(A, 1), LVL - 1);
        ea = make_float4(INF, INF, s_uv[idx - 1], s_uv[idx]);
        eb = make_float4(0.f, 0.f, 0.f, __int_as_float(idx - 1));
    } else if (cnt <= 2 && A >= 1 && A + cnt <= LVL - 1) {
        float p0 = s_uv[A];
        float p1 = (cnt >= 2) ? s_uv[A + 1] : INF;
        float c0 = s_uv[A - 1];
        float c1 = s_uv[A];
        float c2 = s_uv[A + 1];
        float c3 = (A + 2 <= LVL - 1) ? s_uv[A + 2] : 0.f;
        ea = make_float4(p0, p1, c0, c1);
        eb = make_float4(c2, c3, 0.f, __int_as_float(A - 1));
    } else {
        ea = make_float4(0.f, 0.f, 0.f, 0.f);
        eb = make_float4(0.f, 0.f, 0.f, __int_as_float(-(A + 1)));
    }
    lutA[b] = ea;
    lutB[b] = eb;
}

// ---------------- main kernel: NO LDS, NO barrier ----------------
__global__ __launch_bounds__(256) void agc_quant_lut(
    const float* __restrict__ inputs,
    const float* __restrict__ means,
    const float* __restrict__ uv,
    const f32x4* __restrict__ lutA,
    const f32x4* __restrict__ lutB,
    float* __restrict__ out_deq,
    float* __restrict__ out_sym,
    int n4, int n, int nfull)
{
    // uniform scalar loads (L1/L2-hit, broadcast) — same values the build used
    const float lo    = uv[0];
    const float scale = (float)NB / (uv[LVL - 1] - lo);

    int t = threadIdx.x;
    const int i0 = blockIdx.x * (256 * QPT) + t;
    const bool full = (blockIdx.x < nfull);

    // ---- load phase: all 2*QPT streaming loads in flight ----
    f32x4 in[QPT], mn[QPT];
    if (full) {
        #pragma unroll
        for (int k = 0; k < QPT; ++k) {
            int i = i0 + k * 256;
            in[k] = __builtin_nontemporal_load(reinterpret_cast<const f32x4*>(inputs) + i);
            mn[k] = __builtin_nontemporal_load(reinterpret_cast<const f32x4*>(means) + i);
        }
    } else {
        #pragma unroll
        for (int k = 0; k < QPT; ++k) {
            int i = i0 + k * 256;
            if (i < n4) {
                in[k] = __builtin_nontemporal_load(reinterpret_cast<const f32x4*>(inputs) + i);
                mn[k] = __builtin_nontemporal_load(reinterpret_cast<const f32x4*>(means) + i);
            }
        }
    }

    // ---- compute + store per quad ----
    #pragma unroll
    for (int k = 0; k < QPT; ++k) {
        int i = i0 + k * 256;
        if (!full && i >= n4) continue;

        float vs[4] = {in[k].x - mn[k].x, in[k].y - mn[k].y,
                       in[k].z - mn[k].z, in[k].w - mn[k].w};
        float ms[4] = {mn[k].x, mn[k].y, mn[k].z, mn[k].w};
        float dq[4], sy[4];

        // all 4 bucket indices, then all 8 L1 LUT gathers issued together (ILP)
        int bx[4];
        #pragma unroll
        for (int e = 0; e < 4; ++e) bx[e] = bucket_of(vs[e], lo, scale);

        f32x4 A4[4], B4[4];
        #pragma unroll
        for (int e = 0; e < 4; ++e) {
            A4[e] = lutA[bx[e]];
            B4[e] = lutB[bx[e]];
        }

        #pragma unroll
        for (int e = 0; e < 4; ++e) {
            float v = vs[e];
            int bp = __float_as_int(B4[e].w);

            float left, right;
            int base;
            if (bp >= 0) {
                int sel = (A4[e].x < v) + (A4[e].y < v);
                left  = (sel == 0) ? A4[e].z : ((sel == 1) ? A4[e].w : B4[e].x);
                right = (sel == 0) ? A4[e].w : ((sel == 1) ? B4[e].x : B4[e].y);
                base  = bp + sel;
            } else {
                // rare masked path: exact lower_bound scan from valid start
                int s = -bp - 1;
                while (s < LVL && uv[s] < v) ++s;
                int idx = min(max(s, 1), LVL - 1);
                left  = uv[idx - 1];
                right = uv[idx];
                base  = idx - 1;
            }

            bool tl = (fabsf(v - left) <= fabsf(v - right));  // identical to reference
            sy[e] = (float)(base + (tl ? 0 : 1));
            dq[e] = (tl ? left : right) + ms[e];
        }

        reinterpret_cast<float4*>(out_deq)[i] = make_float4(dq[0], dq[1], dq[2], dq[3]);
        reinterpret_cast<float4*>(out_sym)[i] = make_float4(sy[0], sy[1], sy[2], sy[3]);
    }

    // tail (n % 4 != 0) — n here is 12.58M, rem = 0
    if (blockIdx.x == 0 && t == 0) {
        for (int j = n4 * 4; j < n; ++j) {
            float m = means[j];
            float v = inputs[j] - m;
            int l = 0, h = LVL;
            for (int s = 0; s < 8; ++s) {
                int mm = (l + h) >> 1;
                bool r = (uv[mm] < v);
                l = r ? (mm + 1) : l;
                h = r ? h : mm;
            }
            int idx = min(max(l, 1), LVL - 1);
            float left = uv[idx - 1], right = uv[idx];
            bool tl = fabsf(v - left) <= fabsf(v - right);
            out_deq[j] = (tl ? left : right) + m;
            out_sym[j] = (float)(tl ? idx - 1 : idx);
        }
    }
}

// ---------------- safety fallback (no/short workspace): binary-search kernel ----
__global__ __launch_bounds__(256) void agc_quant_fallback(
    const float* __restrict__ inputs,
    const float* __restrict__ means,
    const float* __restrict__ uv,
    float* __restrict__ out_deq,
    float* __restrict__ out_sym,
    int n4, int n)
{
    __shared__ float s_uv[LVL];
    s_uv[threadIdx.x] = uv[threadIdx.x];
    __syncthreads();

    int i = blockIdx.x * blockDim.x + threadIdx.x;
    if (i < n4) {
        float4 in = reinterpret_cast<const float4*>(inputs)[i];
        float4 mn = reinterpret_cast<const float4*>(means)[i];
        float vs[4] = {in.x - mn.x, in.y - mn.y, in.z - mn.z, in.w - mn.w};
        float ms[4] = {mn.x, mn.y, mn.z, mn.w};
        float dq[4], sy[4];
        #pragma unroll
        for (int k = 0; k < 4; ++k) {
            float v = vs[k];
            int lo = 0, hi = LVL;
            #pragma unroll
            for (int s = 0; s < 8; ++s) {
                int mid = (lo + hi) >> 1;
                bool r = (s_uv[mid] < v);
                lo = r ? (mid + 1) : lo;
                hi = r ? hi : mid;
            }
            int idx = min(max(lo, 1), LVL - 1);
            float left = s_uv[idx - 1], right = s_uv[idx];
            bool tl = (fabsf(v - left) <= fabsf(v - right));
            sy[k] = (float)(tl ? idx - 1 : idx);
            dq[k] = (tl ? left : right) + ms[k];
        }
        reinterpret_cast<float4*>(out_deq)[i] = make_float4(dq[0], dq[1], dq[2], dq[3]);
        reinterpret_cast<float4*>(out_sym)[i] = make_float4(sy[0], sy[1], sy[2], sy[3]);
    }
    if (blockIdx.x == 0 && threadIdx.x == 0) {
        for (int j = n4 * 4; j < n; ++j) {
            float m = means[j];
            float v = inputs[j] - m;
            int lo = 0, hi = LVL;
            for (int s = 0; s < 8; ++s) {
                int mid = (lo + hi) >> 1;
                bool r = (s_uv[mid] < v);
                lo = r ? (mid + 1) : lo;
                hi = r ? hi : mid;
            }
            int idx = min(max(lo, 1), LVL - 1);
            float left = s_uv[idx - 1], right = s_uv[idx];
            bool tl = fabsf(v - left) <= fabsf(v - right);
            out_deq[j] = (tl ? left : right) + m;
            out_sym[j] = (float)(tl ? idx - 1 : idx);
        }
    }
}

extern "C" void kernel_launch(void* const* d_in, const int* in_sizes, int n_in,
                              void* d_out, int out_size, void* d_ws, size_t ws_size,
                              hipStream_t stream)
{
    const float* inputs = (const float*)d_in[0];
    const float* means  = (const float*)d_in[1];
    const float* uv     = (const float*)d_in[2];

    int n  = in_sizes[0];        // 12,582,912
    int n4 = n / 4;

    float* out     = (float*)d_out;
    float* out_deq = out;        // first N: dequant
    float* out_sym = out + n;    // second N: symbols (exact float values)

    size_t need = (size_t)NB * 2 * sizeof(float4);   // 16 KB
    if (d_ws != nullptr && ws_size >= need) {
        float4* lutA = (float4*)d_ws;
        float4* lutB = lutA + NB;
        agc_build_lut<<<(NB + 255) / 256, 256, 0, stream>>>(uv, lutA, lutB);

        int per_blk = 256 * QPT;                       // quads per block
        int nfull   = n4 / per_blk;                    // fully-covered blocks
        int blocks  = (n4 + per_blk - 1) / per_blk;    // 3072 for this shape
        if (blocks < 1) blocks = 1;
        agc_quant_lut<<<blocks, 256, 0, stream>>>(
            inputs, means, uv, (const f32x4*)lutA, (const f32x4*)lutB,
            out_deq, out_sym, n4, n, nfull);
    } else {
        int blocks = (n4 + 255) / 256;
        if (blocks < 1) blocks = 1;
        agc_quant_fallback<<<blocks, 256, 0, stream>>>(
            inputs, means, uv, out_deq, out_sym, n4, n);
    }
}